// Round 5
// baseline (351.174 us; speedup 1.0000x reference)
//
#include <hip/hip_runtime.h>
#include <math.h>

#define N4C 32768
#define N3C 65536
#define N2C 131072
#define N1C 262144

typedef _Float16 f16x8 __attribute__((ext_vector_type(8)));
typedef _Float16 f16x4 __attribute__((ext_vector_type(4)));
typedef float f32x4 __attribute__((ext_vector_type(4)));

__device__ __forceinline__ f32x4 mfma16(f16x8 a, f16x8 b, f32x4 c) {
  return __builtin_amdgcn_mfma_f32_16x16x32_f16(a, b, c, 0, 0, 0);
}

// fast celu: expm1(x) ~= __expf(x)-1 (v_exp_f32, abs err ~1e-7)
__device__ __forceinline__ float celuf(float x) {
  return x > 0.f ? x : (__expf(x) - 1.f);
}

// log_sigmoid(x) = min(x,0) - log(1 + exp(-|x|))
__device__ __forceinline__ float logsigf(float x) {
  float e = __expf(-fabsf(x));
  return fminf(x, 0.f) - __logf(1.f + e);
}

// ---------------------------------------------------------------------------
// Prep: z_mask [N4*64] f32 -> zf f16 (4 MB table, L2-cacheable for l3 gathers)
// ---------------------------------------------------------------------------
__global__ __launch_bounds__(256) void zhalf_kernel(const float* __restrict__ z,
                                                    _Float16* __restrict__ zf) {
  const int i = (blockIdx.x * 256 + threadIdx.x) * 4;
  float4 f = *(const float4*)(z + i);
  f16x4 h;
  h[0] = (_Float16)f.x; h[1] = (_Float16)f.y;
  h[2] = (_Float16)f.z; h[3] = (_Float16)f.w;
  *(f16x4*)(zf + i) = h;
}

// ---------------------------------------------------------------------------
// Level 3: PointConv (64 -> 64 -> 32), f16 MFMA, wave per point (16 edges = M).
// Software-pipelined point loop: next point's src + gathers issued before the
// current point's compute so L2 latency hides under MFMA/celu/LDS work.
// ---------------------------------------------------------------------------
__global__ __launch_bounds__(256) void l3_kernel(
    const _Float16* __restrict__ zf, const float* __restrict__ pos4,
    const float* __restrict__ pos3, const int* __restrict__ src3,
    const float* __restrict__ w1a, const float* __restrict__ b1a,
    const float* __restrict__ w1b, const float* __restrict__ b1b,
    _Float16* __restrict__ x3f) {
  __shared__ float hbuf[4][16 * 76];
  const int lane = threadIdx.x & 63;
  const int wid = threadIdx.x >> 6;
  const int col = lane & 15;   // MFMA n / A row m (edge)
  const int quad = lane >> 4;  // k-subchunk selector
  float* hw = hbuf[wid];

  // B frags layer a: B[k][n], k = c*32 + quad*8 + j (K=67 pad 96), n = t*16+col
  f16x8 Ba[3][4];
#pragma unroll
  for (int c = 0; c < 3; ++c)
#pragma unroll
    for (int t = 0; t < 4; ++t)
#pragma unroll
      for (int j = 0; j < 8; ++j) {
        int k = c * 32 + quad * 8 + j;
        Ba[c][t][j] = (k < 67) ? (_Float16)w1a[k * 64 + t * 16 + col] : (_Float16)0.f;
      }
  f16x8 Bb[2][2];
#pragma unroll
  for (int c = 0; c < 2; ++c)
#pragma unroll
    for (int t = 0; t < 2; ++t)
#pragma unroll
      for (int j = 0; j < 8; ++j) {
        int k = c * 32 + quad * 8 + j;
        Bb[c][t][j] = (_Float16)w1b[k * 32 + t * 16 + col];
      }
  const float biasA0 = b1a[col], biasA1 = b1a[16 + col];
  const float biasA2 = b1a[32 + col], biasA3 = b1a[48 + col];
  const float biasB0 = b1b[col], biasB1 = b1b[16 + col];

  const int gwave = blockIdx.x * 4 + wid;
  const int nw = gridDim.x * 4;
  const int iters = (N3C - gwave + nw - 1) / nw;

  // ---- pipeline prologue ----
  int p = gwave;
  int s = __builtin_nontemporal_load(src3 + p * 16 + col);
  f16x8 A0, A1;
  float q0 = 0.f, q1 = 0.f, q2 = 0.f;   // pos4[s] raw (quad 0 lanes)
  float po0, po1, po2;                   // pos3[p]
  {
    const _Float16* zr = zf + (size_t)s * 64;
    A0 = *(const f16x8*)(zr + quad * 8);
    A1 = *(const f16x8*)(zr + 32 + quad * 8);
    if (quad == 0) { q0 = pos4[s * 3]; q1 = pos4[s * 3 + 1]; q2 = pos4[s * 3 + 2]; }
    po0 = pos3[p * 3]; po1 = pos3[p * 3 + 1]; po2 = pos3[p * 3 + 2];
  }
  int pn = p + nw; if (pn >= N3C) pn = p;
  int sn = __builtin_nontemporal_load(src3 + pn * 16 + col);

  f16x8 A2 = {};  // hoisted: only quad0 j0..2 rewritten per iter, rest stay 0

  for (int it = 0; it < iters; ++it) {
    // ---- prefetch next point's gathers (lands under compute below) ----
    f16x8 A0n, A1n;
    float q0n = 0.f, q1n = 0.f, q2n = 0.f, po0n, po1n, po2n;
    {
      const _Float16* zr = zf + (size_t)sn * 64;
      A0n = *(const f16x8*)(zr + quad * 8);
      A1n = *(const f16x8*)(zr + 32 + quad * 8);
      if (quad == 0) { q0n = pos4[sn * 3]; q1n = pos4[sn * 3 + 1]; q2n = pos4[sn * 3 + 2]; }
      po0n = pos3[pn * 3]; po1n = pos3[pn * 3 + 1]; po2n = pos3[pn * 3 + 2];
    }
    int pn2 = pn + nw; if (pn2 >= N3C) pn2 = pn;
    int sn2 = __builtin_nontemporal_load(src3 + pn2 * 16 + col);

    // ---- compute current point p ----
    if (quad == 0) {
      A2[0] = (_Float16)(q0 - po0);
      A2[1] = (_Float16)(q1 - po1);
      A2[2] = (_Float16)(q2 - po2);
    }
    f32x4 d[4];
#pragma unroll
    for (int t = 0; t < 4; ++t) {
      f32x4 acc = {0.f, 0.f, 0.f, 0.f};
      acc = mfma16(A0, Ba[0][t], acc);
      acc = mfma16(A1, Ba[1][t], acc);
      acc = mfma16(A2, Ba[2][t], acc);
      d[t] = acc;
    }
    // C layout: row = quad*4 + r, col = n. celu -> LDS [16][76].
#pragma unroll
    for (int r = 0; r < 4; ++r) {
      float* bp = hw + (quad * 4 + r) * 76 + col;
      bp[0]  = celuf(d[0][r] + biasA0);
      bp[16] = celuf(d[1][r] + biasA1);
      bp[32] = celuf(d[2][r] + biasA2);
      bp[48] = celuf(d[3][r] + biasA3);
    }
    // same-wave LDS, in-order: no barrier. A'[m=col][k=c*32+quad*8+j]
    f16x8 P[2];
#pragma unroll
    for (int c = 0; c < 2; ++c) {
      const float* rp = hw + col * 76 + c * 32 + quad * 8;
      float4 g0 = *(const float4*)rp;
      float4 g1 = *(const float4*)(rp + 4);
      P[c][0] = (_Float16)g0.x; P[c][1] = (_Float16)g0.y;
      P[c][2] = (_Float16)g0.z; P[c][3] = (_Float16)g0.w;
      P[c][4] = (_Float16)g1.x; P[c][5] = (_Float16)g1.y;
      P[c][6] = (_Float16)g1.z; P[c][7] = (_Float16)g1.w;
    }
    f32x4 e[2];
#pragma unroll
    for (int t = 0; t < 2; ++t) {
      f32x4 acc = {0.f, 0.f, 0.f, 0.f};
      acc = mfma16(P[0], Bb[0][t], acc);
      acc = mfma16(P[1], Bb[1][t], acc);
      e[t] = acc;
    }
    float m0 = fmaxf(fmaxf(e[0][0], e[0][1]), fmaxf(e[0][2], e[0][3]));
    float m1 = fmaxf(fmaxf(e[1][0], e[1][1]), fmaxf(e[1][2], e[1][3]));
    m0 = fmaxf(m0, __shfl_xor(m0, 16, 64));
    m0 = fmaxf(m0, __shfl_xor(m0, 32, 64));
    m1 = fmaxf(m1, __shfl_xor(m1, 16, 64));
    m1 = fmaxf(m1, __shfl_xor(m1, 32, 64));
    if (lane < 16) {
      _Float16* row = x3f + (size_t)p * 32;
      row[col]      = (_Float16)celuf(m0 + biasB0);  // max(x)+b == max(x+b)
      row[16 + col] = (_Float16)celuf(m1 + biasB1);
    }
    // ---- rotate pipeline ----
    p = pn; pn = pn2; s = sn; sn = sn2;
    A0 = A0n; A1 = A1n;
    q0 = q0n; q1 = q1n; q2 = q2n;
    po0 = po0n; po1 = po1n; po2 = po2n;
  }
}

// ---------------------------------------------------------------------------
// Level 2: PointConv (32 -> 16 -> 16), f16 MFMA wave-per-point, pipelined.
// ---------------------------------------------------------------------------
__global__ __launch_bounds__(256) void l2_kernel(
    const _Float16* __restrict__ x3f, const float* __restrict__ pos3,
    const float* __restrict__ pos2, const int* __restrict__ src2,
    const float* __restrict__ w2a, const float* __restrict__ b2a,
    const float* __restrict__ w2b, const float* __restrict__ b2b,
    _Float16* __restrict__ x2f) {
  __shared__ float hbuf[4][16 * 20];
  const int lane = threadIdx.x & 63;
  const int wid = threadIdx.x >> 6;
  const int col = lane & 15;
  const int quad = lane >> 4;
  float* hw = hbuf[wid];

  f16x8 Ba0, Ba1, Bb;
#pragma unroll
  for (int j = 0; j < 8; ++j) {
    int k = quad * 8 + j;
    Ba0[j] = (_Float16)w2a[k * 16 + col];                       // k 0..31
    Ba1[j] = (k + 32 < 35) ? (_Float16)w2a[(k + 32) * 16 + col] // k 32..34
                           : (_Float16)0.f;
    Bb[j] = (k < 16) ? (_Float16)w2b[k * 16 + col] : (_Float16)0.f;
  }
  const float biasA = b2a[col];
  const float biasB = b2b[col];

  const int gwave = blockIdx.x * 4 + wid;
  const int nw = gridDim.x * 4;
  const int iters = (N2C - gwave + nw - 1) / nw;

  int p = gwave;
  int s = __builtin_nontemporal_load(src2 + p * 16 + col);
  f16x8 A0;
  float q0 = 0.f, q1 = 0.f, q2 = 0.f, po0, po1, po2;
  {
    A0 = *(const f16x8*)(x3f + (size_t)s * 32 + quad * 8);
    if (quad == 0) { q0 = pos3[s * 3]; q1 = pos3[s * 3 + 1]; q2 = pos3[s * 3 + 2]; }
    po0 = pos2[p * 3]; po1 = pos2[p * 3 + 1]; po2 = pos2[p * 3 + 2];
  }
  int pn = p + nw; if (pn >= N2C) pn = p;
  int sn = __builtin_nontemporal_load(src2 + pn * 16 + col);

  f16x8 A1 = {};  // hoisted zero: quad0 j0..2 rewritten per iter
  f16x8 P = {};   // hoisted zero: quads 0,1 fully rewritten per iter

  for (int it = 0; it < iters; ++it) {
    f16x8 A0n;
    float q0n = 0.f, q1n = 0.f, q2n = 0.f, po0n, po1n, po2n;
    {
      A0n = *(const f16x8*)(x3f + (size_t)sn * 32 + quad * 8);
      if (quad == 0) { q0n = pos3[sn * 3]; q1n = pos3[sn * 3 + 1]; q2n = pos3[sn * 3 + 2]; }
      po0n = pos2[pn * 3]; po1n = pos2[pn * 3 + 1]; po2n = pos2[pn * 3 + 2];
    }
    int pn2 = pn + nw; if (pn2 >= N2C) pn2 = pn;
    int sn2 = __builtin_nontemporal_load(src2 + pn2 * 16 + col);

    // ---- compute current ----
    if (quad == 0) {
      A1[0] = (_Float16)(q0 - po0);
      A1[1] = (_Float16)(q1 - po1);
      A1[2] = (_Float16)(q2 - po2);
    }
    f32x4 d = {0.f, 0.f, 0.f, 0.f};
    d = mfma16(A0, Ba0, d);
    d = mfma16(A1, Ba1, d);
#pragma unroll
    for (int r = 0; r < 4; ++r)
      hw[(quad * 4 + r) * 20 + col] = celuf(d[r] + biasA);

    if (quad < 2) {  // k 0..15 valid
      const float* rp = hw + col * 20 + quad * 8;
      float4 g0 = *(const float4*)rp;
      float4 g1 = *(const float4*)(rp + 4);
      P[0] = (_Float16)g0.x; P[1] = (_Float16)g0.y;
      P[2] = (_Float16)g0.z; P[3] = (_Float16)g0.w;
      P[4] = (_Float16)g1.x; P[5] = (_Float16)g1.y;
      P[6] = (_Float16)g1.z; P[7] = (_Float16)g1.w;
    }
    f32x4 e = {0.f, 0.f, 0.f, 0.f};
    e = mfma16(P, Bb, e);

    float m0 = fmaxf(fmaxf(e[0], e[1]), fmaxf(e[2], e[3]));
    m0 = fmaxf(m0, __shfl_xor(m0, 16, 64));
    m0 = fmaxf(m0, __shfl_xor(m0, 32, 64));
    if (lane < 16) x2f[(size_t)p * 16 + col] = (_Float16)celuf(m0 + biasB);

    p = pn; pn = pn2; s = sn; sn = sn2;
    A0 = A0n; q0 = q0n; q1 = q1n; q2 = q2n;
    po0 = po0n; po1 = po1n; po2 = po2n;
  }
}

// ---------------------------------------------------------------------------
// Level 1: PointConv (16 -> 8 -> 8) + final linear + log_sigmoid, pipelined.
// ---------------------------------------------------------------------------
__global__ __launch_bounds__(256) void l1_kernel(
    const _Float16* __restrict__ x2f, const float* __restrict__ pos2,
    const float* __restrict__ pos1, const int* __restrict__ src1,
    const float* __restrict__ w3a, const float* __restrict__ b3a,
    const float* __restrict__ w3b, const float* __restrict__ b3b,
    const float* __restrict__ wlin, const float* __restrict__ blin,
    float* __restrict__ out) {
  __shared__ float hbuf[4][16 * 12];
  const int lane = threadIdx.x & 63;
  const int wid = threadIdx.x >> 6;
  const int col = lane & 15;
  const int quad = lane >> 4;
  float* hw = hbuf[wid];

  f16x8 Ba, Bb;
#pragma unroll
  for (int j = 0; j < 8; ++j) {
    int k = quad * 8 + j;
    Ba[j] = (k < 19 && col < 8) ? (_Float16)w3a[k * 8 + col] : (_Float16)0.f;
    Bb[j] = (k < 8 && col < 8) ? (_Float16)w3b[k * 8 + col] : (_Float16)0.f;
  }
  const float biasA = (col < 8) ? b3a[col] : 0.f;
  const float biasB = (col < 8) ? b3b[col] : 0.f;
  const float wl = (col < 8) ? wlin[col] : 0.f;
  const float bl = blin[0];

  const int gwave = blockIdx.x * 4 + wid;
  const int nw = gridDim.x * 4;
  const int iters = (N1C - gwave + nw - 1) / nw;

  int p = gwave;
  int s = __builtin_nontemporal_load(src1 + p * 16 + col);
  f16x8 A0;                               // quads 0,1: feature halves
  float q0 = 0.f, q1 = 0.f, q2 = 0.f;     // quad 2: pos2[s] raw
  float po0, po1, po2;                    // pos1[p]
  {
    if (quad < 2) A0 = *(const f16x8*)(x2f + (size_t)s * 16 + quad * 8);
    if (quad == 2) { q0 = pos2[s * 3]; q1 = pos2[s * 3 + 1]; q2 = pos2[s * 3 + 2]; }
    po0 = pos1[p * 3]; po1 = pos1[p * 3 + 1]; po2 = pos1[p * 3 + 2];
  }
  int pn = p + nw; if (pn >= N1C) pn = p;
  int sn = __builtin_nontemporal_load(src1 + pn * 16 + col);

  f16x8 A = {};  // hoisted zero: quad3 all-zero, quad2 j3..7 zero
  f16x8 P = {};  // hoisted zero: quad0 fully rewritten per iter

  for (int it = 0; it < iters; ++it) {
    f16x8 A0n;
    float q0n = 0.f, q1n = 0.f, q2n = 0.f, po0n, po1n, po2n;
    {
      if (quad < 2) A0n = *(const f16x8*)(x2f + (size_t)sn * 16 + quad * 8);
      if (quad == 2) { q0n = pos2[sn * 3]; q1n = pos2[sn * 3 + 1]; q2n = pos2[sn * 3 + 2]; }
      po0n = pos1[pn * 3]; po1n = pos1[pn * 3 + 1]; po2n = pos1[pn * 3 + 2];
    }
    int pn2 = pn + nw; if (pn2 >= N1C) pn2 = pn;
    int sn2 = __builtin_nontemporal_load(src1 + pn2 * 16 + col);

    // ---- compute current ----
    if (quad < 2) {
      A = A0;
    } else if (quad == 2) {
      A[0] = (_Float16)(q0 - po0);
      A[1] = (_Float16)(q1 - po1);
      A[2] = (_Float16)(q2 - po2);
    }
    f32x4 d = {0.f, 0.f, 0.f, 0.f};
    d = mfma16(A, Ba, d);

    if (col < 8) {
#pragma unroll
      for (int r = 0; r < 4; ++r)
        hw[(quad * 4 + r) * 12 + col] = celuf(d[r] + biasA);
    }
    if (quad == 0) {  // k = 0..7 valid
      const float* rp = hw + col * 12;
      float4 g0 = *(const float4*)rp;
      float4 g1 = *(const float4*)(rp + 4);
      P[0] = (_Float16)g0.x; P[1] = (_Float16)g0.y;
      P[2] = (_Float16)g0.z; P[3] = (_Float16)g0.w;
      P[4] = (_Float16)g1.x; P[5] = (_Float16)g1.y;
      P[6] = (_Float16)g1.z; P[7] = (_Float16)g1.w;
    }
    f32x4 e = {0.f, 0.f, 0.f, 0.f};
    e = mfma16(P, Bb, e);

    float m0 = fmaxf(fmaxf(e[0], e[1]), fmaxf(e[2], e[3]));
    m0 = fmaxf(m0, __shfl_xor(m0, 16, 64));
    m0 = fmaxf(m0, __shfl_xor(m0, 32, 64));
    // final linear + log_sigmoid: lane0 needs sum of cols 0..7 -> 3 shuffles
    float t = (col < 8) ? celuf(m0 + biasB) * wl : 0.f;
    t += __shfl_xor(t, 1, 64);
    t += __shfl_xor(t, 2, 64);
    t += __shfl_xor(t, 4, 64);
    if (lane == 0) out[p] = logsigf(t + bl);

    p = pn; pn = pn2; s = sn; sn = sn2;
    A0 = A0n; q0 = q0n; q1 = q1n; q2 = q2n;
    po0 = po0n; po1 = po1n; po2 = po2n;
  }
}

extern "C" void kernel_launch(void* const* d_in, const int* in_sizes, int n_in,
                              void* d_out, int out_size, void* d_ws, size_t ws_size,
                              hipStream_t stream) {
  const float* z_mask = (const float*)d_in[0];
  const float* pos4 = (const float*)d_in[1];
  const float* pos3 = (const float*)d_in[2];
  const float* pos2 = (const float*)d_in[3];
  const float* pos1 = (const float*)d_in[4];
  const float* w1a = (const float*)d_in[9];
  const float* b1a = (const float*)d_in[10];
  const float* w1b = (const float*)d_in[11];
  const float* b1b = (const float*)d_in[12];
  const float* w2a = (const float*)d_in[13];
  const float* b2a = (const float*)d_in[14];
  const float* w2b = (const float*)d_in[15];
  const float* b2b = (const float*)d_in[16];
  const float* w3a = (const float*)d_in[17];
  const float* b3a = (const float*)d_in[18];
  const float* w3b = (const float*)d_in[19];
  const float* b3b = (const float*)d_in[20];
  const float* wlin = (const float*)d_in[21];
  const float* blin = (const float*)d_in[22];
  const int* src3 = (const int*)d_in[23];
  const int* src2 = (const int*)d_in[25];
  const int* src1 = (const int*)d_in[27];

  // ws layout: [x3f 4 MB][regionB 4 MB]
  // regionB: zf (live prep..l3) then x2f (live l2..l1) — disjoint lifetimes.
  _Float16* x3f = (_Float16*)d_ws;                                 // [N3][32] f16
  _Float16* zf = (_Float16*)((char*)d_ws + (size_t)N3C * 32 * 2);  // [N4][64] f16
  _Float16* x2f = zf;                                              // [N2][16] f16
  float* out = (float*)d_out;

  zhalf_kernel<<<(N4C * 64) / (256 * 4), 256, 0, stream>>>(z_mask, zf);
  l3_kernel<<<2048, 256, 0, stream>>>(zf, pos4, pos3, src3, w1a, b1a, w1b, b1b, x3f);
  l2_kernel<<<8192, 256, 0, stream>>>(x3f, pos3, pos2, src2, w2a, b2a, w2b, b2b, x2f);
  l1_kernel<<<8192, 256, 0, stream>>>(x2f, pos2, pos1, src1, w3a, b3a, w3b, b3b,
                                      wlin, blin, out);
}

// Round 6
// 341.522 us; speedup vs baseline: 1.0283x; 1.0283x over previous
//
#include <hip/hip_runtime.h>
#include <math.h>

#define N4C 32768
#define N3C 65536
#define N2C 131072
#define N1C 262144

typedef _Float16 f16x8 __attribute__((ext_vector_type(8)));
typedef _Float16 f16x4 __attribute__((ext_vector_type(4)));
typedef float f32x4 __attribute__((ext_vector_type(4)));

__device__ __forceinline__ f32x4 mfma16(f16x8 a, f16x8 b, f32x4 c) {
  return __builtin_amdgcn_mfma_f32_16x16x32_f16(a, b, c, 0, 0, 0);
}

// fast celu: expm1(x) ~= __expf(x)-1 (v_exp_f32, abs err ~1e-7)
__device__ __forceinline__ float celuf(float x) {
  return x > 0.f ? x : (__expf(x) - 1.f);
}

// log_sigmoid(x) = min(x,0) - log(1 + exp(-|x|))
__device__ __forceinline__ float logsigf(float x) {
  float e = __expf(-fabsf(x));
  return fminf(x, 0.f) - __logf(1.f + e);
}

// ---------------------------------------------------------------------------
// Prep: z_mask [N4*64] f32 -> zf f16 (4 MB table for l3 gathers)
// ---------------------------------------------------------------------------
__global__ __launch_bounds__(256) void zhalf_kernel(const float* __restrict__ z,
                                                    _Float16* __restrict__ zf) {
  const int i = (blockIdx.x * 256 + threadIdx.x) * 4;
  float4 f = *(const float4*)(z + i);
  f16x4 h;
  h[0] = (_Float16)f.x; h[1] = (_Float16)f.y;
  h[2] = (_Float16)f.z; h[3] = (_Float16)f.w;
  *(f16x4*)(zf + i) = h;
}

// ---------------------------------------------------------------------------
// Level 3: PointConv (64 -> 64 -> 32), f16 MFMA, wave per point (16 edges = M).
// All 8 src indices preloaded at entry; U=2 points per iteration with grouped
// load phase so two gather chains are always concurrently in flight
// (robust even if the compiler emits vmcnt(0) before the first MFMA).
// ---------------------------------------------------------------------------
__global__ __launch_bounds__(256) void l3_kernel(
    const _Float16* __restrict__ zf, const float* __restrict__ pos4,
    const float* __restrict__ pos3, const int* __restrict__ src3,
    const float* __restrict__ w1a, const float* __restrict__ b1a,
    const float* __restrict__ w1b, const float* __restrict__ b1b,
    _Float16* __restrict__ x3f) {
  __shared__ float hbuf[4][16 * 76];
  const int lane = threadIdx.x & 63;
  const int wid = threadIdx.x >> 6;
  const int col = lane & 15;   // MFMA n / A row m (edge)
  const int quad = lane >> 4;  // k-subchunk selector
  float* hw = hbuf[wid];

  // B frags layer a: B[k][n], k = c*32 + quad*8 + j (K=67 pad 96), n = t*16+col
  f16x8 Ba[3][4];
#pragma unroll
  for (int c = 0; c < 3; ++c)
#pragma unroll
    for (int t = 0; t < 4; ++t)
#pragma unroll
      for (int j = 0; j < 8; ++j) {
        int k = c * 32 + quad * 8 + j;
        Ba[c][t][j] = (k < 67) ? (_Float16)w1a[k * 64 + t * 16 + col] : (_Float16)0.f;
      }
  f16x8 Bb[2][2];
#pragma unroll
  for (int c = 0; c < 2; ++c)
#pragma unroll
    for (int t = 0; t < 2; ++t)
#pragma unroll
      for (int j = 0; j < 8; ++j) {
        int k = c * 32 + quad * 8 + j;
        Bb[c][t][j] = (_Float16)w1b[k * 32 + t * 16 + col];
      }
  const float biasA0 = b1a[col], biasA1 = b1a[16 + col];
  const float biasA2 = b1a[32 + col], biasA3 = b1a[48 + col];
  const float biasB0 = b1b[col], biasB1 = b1b[16 + col];

  const int gwave = blockIdx.x * 4 + wid;
  const int nw = gridDim.x * 4;  // 8192 waves -> 8 points/wave exactly

  // preload all src indices: removes src load from every chain
  int s[8];
#pragma unroll
  for (int i = 0; i < 8; ++i) s[i] = src3[(gwave + i * nw) * 16 + col];

  f16x8 A2 = {};  // only quad0 j0..2 rewritten per point; rest stay 0

#pragma unroll 1
  for (int i0 = 0; i0 < 8; i0 += 2) {
    // ---- load phase: both points' gathers issued back-to-back ----
    f16x8 A0[2], A1[2];
    float q0[2], q1[2], q2[2], po0[2], po1[2], po2[2];
#pragma unroll
    for (int u = 0; u < 2; ++u) {
      const int su = s[i0 + u];
      const int p = gwave + (i0 + u) * nw;
      const _Float16* zr = zf + (size_t)su * 64;
      A0[u] = *(const f16x8*)(zr + quad * 8);
      A1[u] = *(const f16x8*)(zr + 32 + quad * 8);
      q0[u] = 0.f; q1[u] = 0.f; q2[u] = 0.f;
      if (quad == 0) {
        q0[u] = pos4[su * 3]; q1[u] = pos4[su * 3 + 1]; q2[u] = pos4[su * 3 + 2];
      }
      po0[u] = pos3[p * 3]; po1[u] = pos3[p * 3 + 1]; po2[u] = pos3[p * 3 + 2];
    }
    // ---- compute phase ----
#pragma unroll
    for (int u = 0; u < 2; ++u) {
      const int p = gwave + (i0 + u) * nw;
      if (quad == 0) {
        A2[0] = (_Float16)(q0[u] - po0[u]);
        A2[1] = (_Float16)(q1[u] - po1[u]);
        A2[2] = (_Float16)(q2[u] - po2[u]);
      }
      f32x4 d[4];
#pragma unroll
      for (int t = 0; t < 4; ++t) {
        f32x4 acc = {0.f, 0.f, 0.f, 0.f};
        acc = mfma16(A0[u], Ba[0][t], acc);
        acc = mfma16(A1[u], Ba[1][t], acc);
        acc = mfma16(A2, Ba[2][t], acc);
        d[t] = acc;
      }
      // C layout: row = quad*4 + r, col = n. celu -> LDS [16][76].
#pragma unroll
      for (int r = 0; r < 4; ++r) {
        float* bp = hw + (quad * 4 + r) * 76 + col;
        bp[0]  = celuf(d[0][r] + biasA0);
        bp[16] = celuf(d[1][r] + biasA1);
        bp[32] = celuf(d[2][r] + biasA2);
        bp[48] = celuf(d[3][r] + biasA3);
      }
      // same-wave LDS, in-order: no barrier. A'[m=col][k=c*32+quad*8+j]
      f16x8 P[2];
#pragma unroll
      for (int c = 0; c < 2; ++c) {
        const float* rp = hw + col * 76 + c * 32 + quad * 8;
        float4 g0 = *(const float4*)rp;
        float4 g1 = *(const float4*)(rp + 4);
        P[c][0] = (_Float16)g0.x; P[c][1] = (_Float16)g0.y;
        P[c][2] = (_Float16)g0.z; P[c][3] = (_Float16)g0.w;
        P[c][4] = (_Float16)g1.x; P[c][5] = (_Float16)g1.y;
        P[c][6] = (_Float16)g1.z; P[c][7] = (_Float16)g1.w;
      }
      f32x4 e[2];
#pragma unroll
      for (int t = 0; t < 2; ++t) {
        f32x4 acc = {0.f, 0.f, 0.f, 0.f};
        acc = mfma16(P[0], Bb[0][t], acc);
        acc = mfma16(P[1], Bb[1][t], acc);
        e[t] = acc;
      }
      float m0 = fmaxf(fmaxf(e[0][0], e[0][1]), fmaxf(e[0][2], e[0][3]));
      float m1 = fmaxf(fmaxf(e[1][0], e[1][1]), fmaxf(e[1][2], e[1][3]));
      m0 = fmaxf(m0, __shfl_xor(m0, 16, 64));
      m0 = fmaxf(m0, __shfl_xor(m0, 32, 64));
      m1 = fmaxf(m1, __shfl_xor(m1, 16, 64));
      m1 = fmaxf(m1, __shfl_xor(m1, 32, 64));
      if (lane < 16) {
        _Float16* row = x3f + (size_t)p * 32;
        row[col]      = (_Float16)celuf(m0 + biasB0);  // max(x)+b == max(x+b)
        row[16 + col] = (_Float16)celuf(m1 + biasB1);
      }
    }
  }
}

// ---------------------------------------------------------------------------
// Level 2: PointConv (32 -> 16 -> 16), f16 MFMA wave-per-point; src preload +
// U=2 grouped chains.
// ---------------------------------------------------------------------------
__global__ __launch_bounds__(256) void l2_kernel(
    const _Float16* __restrict__ x3f, const float* __restrict__ pos3,
    const float* __restrict__ pos2, const int* __restrict__ src2,
    const float* __restrict__ w2a, const float* __restrict__ b2a,
    const float* __restrict__ w2b, const float* __restrict__ b2b,
    _Float16* __restrict__ x2f) {
  __shared__ float hbuf[4][16 * 20];
  const int lane = threadIdx.x & 63;
  const int wid = threadIdx.x >> 6;
  const int col = lane & 15;
  const int quad = lane >> 4;
  float* hw = hbuf[wid];

  f16x8 Ba0, Ba1, Bb;
#pragma unroll
  for (int j = 0; j < 8; ++j) {
    int k = quad * 8 + j;
    Ba0[j] = (_Float16)w2a[k * 16 + col];                       // k 0..31
    Ba1[j] = (k + 32 < 35) ? (_Float16)w2a[(k + 32) * 16 + col] // k 32..34
                           : (_Float16)0.f;
    Bb[j] = (k < 16) ? (_Float16)w2b[k * 16 + col] : (_Float16)0.f;
  }
  const float biasA = b2a[col];
  const float biasB = b2b[col];

  const int gwave = blockIdx.x * 4 + wid;
  const int nw = gridDim.x * 4;  // 32768 waves -> 4 points/wave exactly

  int s[4];
#pragma unroll
  for (int i = 0; i < 4; ++i) s[i] = src2[(gwave + i * nw) * 16 + col];

  f16x8 A1 = {};  // quad0 j0..2 rewritten per point
  f16x8 P = {};   // quads 0,1 fully rewritten per point

#pragma unroll 1
  for (int i0 = 0; i0 < 4; i0 += 2) {
    f16x8 A0[2];
    float q0[2], q1[2], q2[2], po0[2], po1[2], po2[2];
#pragma unroll
    for (int u = 0; u < 2; ++u) {
      const int su = s[i0 + u];
      const int p = gwave + (i0 + u) * nw;
      A0[u] = *(const f16x8*)(x3f + (size_t)su * 32 + quad * 8);
      q0[u] = 0.f; q1[u] = 0.f; q2[u] = 0.f;
      if (quad == 0) {
        q0[u] = pos3[su * 3]; q1[u] = pos3[su * 3 + 1]; q2[u] = pos3[su * 3 + 2];
      }
      po0[u] = pos2[p * 3]; po1[u] = pos2[p * 3 + 1]; po2[u] = pos2[p * 3 + 2];
    }
#pragma unroll
    for (int u = 0; u < 2; ++u) {
      const int p = gwave + (i0 + u) * nw;
      if (quad == 0) {
        A1[0] = (_Float16)(q0[u] - po0[u]);
        A1[1] = (_Float16)(q1[u] - po1[u]);
        A1[2] = (_Float16)(q2[u] - po2[u]);
      }
      f32x4 d = {0.f, 0.f, 0.f, 0.f};
      d = mfma16(A0[u], Ba0, d);
      d = mfma16(A1, Ba1, d);
#pragma unroll
      for (int r = 0; r < 4; ++r)
        hw[(quad * 4 + r) * 20 + col] = celuf(d[r] + biasA);

      if (quad < 2) {  // k 0..15 valid
        const float* rp = hw + col * 20 + quad * 8;
        float4 g0 = *(const float4*)rp;
        float4 g1 = *(const float4*)(rp + 4);
        P[0] = (_Float16)g0.x; P[1] = (_Float16)g0.y;
        P[2] = (_Float16)g0.z; P[3] = (_Float16)g0.w;
        P[4] = (_Float16)g1.x; P[5] = (_Float16)g1.y;
        P[6] = (_Float16)g1.z; P[7] = (_Float16)g1.w;
      }
      f32x4 e = {0.f, 0.f, 0.f, 0.f};
      e = mfma16(P, Bb, e);

      float m0 = fmaxf(fmaxf(e[0], e[1]), fmaxf(e[2], e[3]));
      m0 = fmaxf(m0, __shfl_xor(m0, 16, 64));
      m0 = fmaxf(m0, __shfl_xor(m0, 32, 64));
      if (lane < 16) x2f[(size_t)p * 16 + col] = (_Float16)celuf(m0 + biasB);
    }
  }
}

// ---------------------------------------------------------------------------
// Level 1: PointConv (16 -> 8 -> 8) + final linear + log_sigmoid; src preload
// + U=4 grouped chains (4 gathers concurrently in flight per wave).
// ---------------------------------------------------------------------------
__global__ __launch_bounds__(256) void l1_kernel(
    const _Float16* __restrict__ x2f, const float* __restrict__ pos2,
    const float* __restrict__ pos1, const int* __restrict__ src1,
    const float* __restrict__ w3a, const float* __restrict__ b3a,
    const float* __restrict__ w3b, const float* __restrict__ b3b,
    const float* __restrict__ wlin, const float* __restrict__ blin,
    float* __restrict__ out) {
  __shared__ float hbuf[4][16 * 12];
  const int lane = threadIdx.x & 63;
  const int wid = threadIdx.x >> 6;
  const int col = lane & 15;
  const int quad = lane >> 4;
  float* hw = hbuf[wid];

  f16x8 Ba, Bb;
#pragma unroll
  for (int j = 0; j < 8; ++j) {
    int k = quad * 8 + j;
    Ba[j] = (k < 19 && col < 8) ? (_Float16)w3a[k * 8 + col] : (_Float16)0.f;
    Bb[j] = (k < 8 && col < 8) ? (_Float16)w3b[k * 8 + col] : (_Float16)0.f;
  }
  const float biasA = (col < 8) ? b3a[col] : 0.f;
  const float biasB = (col < 8) ? b3b[col] : 0.f;
  const float wl = (col < 8) ? wlin[col] : 0.f;
  const float bl = blin[0];

  const int gwave = blockIdx.x * 4 + wid;
  const int nw = gridDim.x * 4;  // 32768 waves -> 8 points/wave exactly

  int s[8];
#pragma unroll
  for (int i = 0; i < 8; ++i) s[i] = src1[(gwave + i * nw) * 16 + col];

  f16x8 P = {};  // quad0 fully rewritten per point

#pragma unroll 1
  for (int i0 = 0; i0 < 8; i0 += 4) {
    // ---- load phase: 4 points' gathers in flight together ----
    f16x8 A0[4];
    float q0[4], q1[4], q2[4], po0[4], po1[4], po2[4];
#pragma unroll
    for (int u = 0; u < 4; ++u) {
      const int su = s[i0 + u];
      const int p = gwave + (i0 + u) * nw;
      if (quad < 2) A0[u] = *(const f16x8*)(x2f + (size_t)su * 16 + quad * 8);
      q0[u] = 0.f; q1[u] = 0.f; q2[u] = 0.f;
      if (quad == 2) {
        q0[u] = pos2[su * 3]; q1[u] = pos2[su * 3 + 1]; q2[u] = pos2[su * 3 + 2];
      }
      po0[u] = pos1[p * 3]; po1[u] = pos1[p * 3 + 1]; po2[u] = pos1[p * 3 + 2];
    }
    // ---- compute phase ----
#pragma unroll
    for (int u = 0; u < 4; ++u) {
      const int p = gwave + (i0 + u) * nw;
      f16x8 A = {};
      if (quad < 2) {
        A = A0[u];
      } else if (quad == 2) {
        A[0] = (_Float16)(q0[u] - po0[u]);
        A[1] = (_Float16)(q1[u] - po1[u]);
        A[2] = (_Float16)(q2[u] - po2[u]);
      }
      f32x4 d = {0.f, 0.f, 0.f, 0.f};
      d = mfma16(A, Ba, d);

      if (col < 8) {
#pragma unroll
        for (int r = 0; r < 4; ++r)
          hw[(quad * 4 + r) * 12 + col] = celuf(d[r] + biasA);
      }
      if (quad == 0) {  // k = 0..7 valid
        const float* rp = hw + col * 12;
        float4 g0 = *(const float4*)rp;
        float4 g1 = *(const float4*)(rp + 4);
        P[0] = (_Float16)g0.x; P[1] = (_Float16)g0.y;
        P[2] = (_Float16)g0.z; P[3] = (_Float16)g0.w;
        P[4] = (_Float16)g1.x; P[5] = (_Float16)g1.y;
        P[6] = (_Float16)g1.z; P[7] = (_Float16)g1.w;
      }
      f32x4 e = {0.f, 0.f, 0.f, 0.f};
      e = mfma16(P, Bb, e);

      float m0 = fmaxf(fmaxf(e[0], e[1]), fmaxf(e[2], e[3]));
      m0 = fmaxf(m0, __shfl_xor(m0, 16, 64));
      m0 = fmaxf(m0, __shfl_xor(m0, 32, 64));
      // lane0 needs sum over cols 0..7 (cols 8..15 contribute 0)
      float t = (col < 8) ? celuf(m0 + biasB) * wl : 0.f;
      t += __shfl_xor(t, 1, 64);
      t += __shfl_xor(t, 2, 64);
      t += __shfl_xor(t, 4, 64);
      if (lane == 0) out[p] = logsigf(t + bl);
    }
  }
}

extern "C" void kernel_launch(void* const* d_in, const int* in_sizes, int n_in,
                              void* d_out, int out_size, void* d_ws, size_t ws_size,
                              hipStream_t stream) {
  const float* z_mask = (const float*)d_in[0];
  const float* pos4 = (const float*)d_in[1];
  const float* pos3 = (const float*)d_in[2];
  const float* pos2 = (const float*)d_in[3];
  const float* pos1 = (const float*)d_in[4];
  const float* w1a = (const float*)d_in[9];
  const float* b1a = (const float*)d_in[10];
  const float* w1b = (const float*)d_in[11];
  const float* b1b = (const float*)d_in[12];
  const float* w2a = (const float*)d_in[13];
  const float* b2a = (const float*)d_in[14];
  const float* w2b = (const float*)d_in[15];
  const float* b2b = (const float*)d_in[16];
  const float* w3a = (const float*)d_in[17];
  const float* b3a = (const float*)d_in[18];
  const float* w3b = (const float*)d_in[19];
  const float* b3b = (const float*)d_in[20];
  const float* wlin = (const float*)d_in[21];
  const float* blin = (const float*)d_in[22];
  const int* src3 = (const int*)d_in[23];
  const int* src2 = (const int*)d_in[25];
  const int* src1 = (const int*)d_in[27];

  // ws layout: [x3f 4 MB][regionB 4 MB]
  // regionB: zf (live prep..l3) then x2f (live l2..l1) — disjoint lifetimes.
  _Float16* x3f = (_Float16*)d_ws;                                 // [N3][32] f16
  _Float16* zf = (_Float16*)((char*)d_ws + (size_t)N3C * 32 * 2);  // [N4][64] f16
  _Float16* x2f = zf;                                              // [N2][16] f16
  float* out = (float*)d_out;

  zhalf_kernel<<<(N4C * 64) / (256 * 4), 256, 0, stream>>>(z_mask, zf);
  l3_kernel<<<2048, 256, 0, stream>>>(zf, pos4, pos3, src3, w1a, b1a, w1b, b1b, x3f);
  l2_kernel<<<8192, 256, 0, stream>>>(x3f, pos3, pos2, src2, w2a, b2a, w2b, b2b, x2f);
  l1_kernel<<<8192, 256, 0, stream>>>(x2f, pos2, pos1, src1, w3a, b3a, w3b, b3b,
                                      wlin, blin, out);
}